// Round 4
// baseline (422.193 us; speedup 1.0000x reference)
//
#include <hip/hip_runtime.h>

// PPO model loss — wave-autonomous 3-level GAE decomposition, no block-wide
// scans, finalize folded into loss kernel via completion counter.
//
// A1 seg_stats : per-segment (256 elems / wave) affine (L, c^256) + whitening
//                sums as closed-form coeffs in the segment carry C:
//                s1_seg = b0 + b1*C ; s2_seg = q0 + q1*C + q2*C^2
// A2 compose   : per-row serial composition of 16 segment affines -> carries
//                wsC[row][seg]; accumulates global sum/sumsq via coeffs.
// B  loss      : per-segment wave regenerates adv from wsC + 64-lane shfl
//                scan, computes clipped vf/pg losses; last block finalizes.
//
// ws layout: [0..47] double acc: 0=s1 1=s2 2=vf 3=pg 4=n 5=counter(ull)
//            [64..]  8 float arrays of NS=rows*16: L,M,b0,b1,q0,q1,q2,C

static constexpr int T_DIM = 4096;
static constexpr int SEG   = 256;           // elements per segment (one wave)
static constexpr int NSEG  = T_DIM / SEG;   // 16 segments per row
static constexpr int CH    = 4;             // elements per lane
static constexpr int BT    = 256;           // threads per block
static constexpr int NW    = BT / 64;       // 4 waves per block

#define CDEC 0.95f
#define CLIPR 0.2f
#define CLIPV 0.2f

__device__ __forceinline__ double wave_sum_d(double v) {
#pragma unroll
  for (int d = 32; d > 0; d >>= 1) v += __shfl_down(v, d);
  return v;
}

__device__ __forceinline__ float wave_sum_f(float v) {
#pragma unroll
  for (int d = 32; d > 0; d >>= 1) v += __shfl_down(v, d);
  return v;
}

// inclusive suffix scan of affine (L, M) across the 64-lane wave:
// lane k ends with composition of lanes k..63.
__device__ __forceinline__ void wave_suffix(float& sL, float& sM, int lane) {
#pragma unroll
  for (int d = 1; d < 64; d <<= 1) {
    float oL = __shfl_down(sL, d);
    float oM = __shfl_down(sM, d);
    if (lane + d < 64) { sL += sM * oL; sM *= oM; }
  }
}

// ---------------- A1: per-segment affine + stats coefficients --------------
__global__ __launch_bounds__(BT) void seg_stats_kernel(
    const float* __restrict__ old_values,
    const float* __restrict__ rewards,
    float* __restrict__ wsL, float* __restrict__ wsM,
    float* __restrict__ wsB0, float* __restrict__ wsB1,
    float* __restrict__ wsQ0, float* __restrict__ wsQ1,
    float* __restrict__ wsQ2) {
  const int tid  = threadIdx.x;
  const int lane = tid & 63;
  const int gw   = blockIdx.x * NW + (tid >> 6);  // segment id
  const int row  = gw >> 4, seg = gw & (NSEG - 1);
  const float c  = CDEC;
  const long base = (long)row * T_DIM + seg * SEG + (long)lane * CH;

  const float4 rv = *(const float4*)(rewards + base);
  const float4 vv = *(const float4*)(old_values + base);
  float nv = __shfl_down(vv.x, 1);
  if (lane == 63) nv = (seg == NSEG - 1) ? 0.f : old_values[base + CH];

  const float c2 = c * c, c3 = c2 * c, c4 = c2 * c2;
  const float Qc = c + c2 + c3 + c4;                    // sum c^i, i=1..4
  const float Q2 = c2 + c4 + c4 * c2 + c4 * c4;         // sum c^(2i)

  // local suffix chain (t high -> low) with closed-form stat accumulators
  float L = 0.f, P = 0.f, P2 = 0.f, cross = 0.f, pw = 1.f, d;
  d = rv.w + nv - vv.w; L = d + c * L; pw *= c; P += L; P2 += L * L; cross += L * pw; nv = vv.w;
  d = rv.z + nv - vv.z; L = d + c * L; pw *= c; P += L; P2 += L * L; cross += L * pw; nv = vv.z;
  d = rv.y + nv - vv.y; L = d + c * L; pw *= c; P += L; P2 += L * L; cross += L * pw; nv = vv.y;
  d = rv.x + nv - vv.x; L = d + c * L; pw *= c; P += L; P2 += L * L; cross += L * pw;

  float sL = L, sM = c4;
  wave_suffix(sL, sM, lane);
  float nL = __shfl_down(sL, 1);
  float nM = __shfl_down(sM, 1);
  if (lane == 63) { nL = 0.f; nM = 1.f; }

  // thread carry = nL + nM*C  =>  stats as polynomials in segment carry C
  float b0 = P + Qc * nL;
  float b1 = Qc * nM;
  float q0 = P2 + 2.f * nL * cross + Q2 * nL * nL;
  float q1 = 2.f * nM * cross + 2.f * Q2 * nL * nM;
  float q2 = Q2 * nM * nM;

  b0 = wave_sum_f(b0); b1 = wave_sum_f(b1);
  q0 = wave_sum_f(q0); q1 = wave_sum_f(q1); q2 = wave_sum_f(q2);

  if (lane == 0) {
    wsL[gw] = sL;  wsM[gw] = sM;    // segment affine (lane0: full 256-elem)
    wsB0[gw] = b0; wsB1[gw] = b1;
    wsQ0[gw] = q0; wsQ1[gw] = q1; wsQ2[gw] = q2;
  }
}

// ---------------- A2: per-row composition + global stats -------------------
__global__ __launch_bounds__(BT) void compose_kernel(
    const float* __restrict__ wsL, const float* __restrict__ wsM,
    const float* __restrict__ wsB0, const float* __restrict__ wsB1,
    const float* __restrict__ wsQ0, const float* __restrict__ wsQ1,
    const float* __restrict__ wsQ2,
    float* __restrict__ wsC, double* __restrict__ acc, int nrows) {
  const int tid  = threadIdx.x;
  const int lane = tid & 63;
  const int wave = tid >> 6;
  const int row  = blockIdx.x * BT + tid;

  double s1 = 0.0, s2 = 0.0;
  if (row < nrows) {
    const int i0 = row * NSEG;
    float C = 0.f;   // carry into segment s (starts at last segment)
    for (int s = NSEG - 1; s >= 0; --s) {
      wsC[i0 + s] = C;
      s1 += (double)(wsB0[i0 + s] + wsB1[i0 + s] * C);
      s2 += (double)(wsQ0[i0 + s] + (wsQ1[i0 + s] + wsQ2[i0 + s] * C) * C);
      C = wsL[i0 + s] + wsM[i0 + s] * C;   // becomes carry into segment s-1
    }
  }

  __shared__ double red[2][NW];
  double r1 = wave_sum_d(s1);
  double r2 = wave_sum_d(s2);
  if (lane == 0) { red[0][wave] = r1; red[1][wave] = r2; }
  __syncthreads();
  if (tid == 0) {
    double t1 = 0.0, t2 = 0.0;
#pragma unroll
    for (int w = 0; w < NW; ++w) { t1 += red[0][w]; t2 += red[1][w]; }
    atomicAdd(&acc[0], t1);
    atomicAdd(&acc[1], t2);
  }
}

// ---------------- B: losses + in-kernel finalize ---------------------------
__global__ __launch_bounds__(BT) void loss_kernel(
    const float* __restrict__ logprobs,
    const float* __restrict__ values,
    const float* __restrict__ old_logprobs,
    const float* __restrict__ old_values,
    const float* __restrict__ rewards,
    const int*   __restrict__ mask,
    const float* __restrict__ wsC,
    double* __restrict__ acc, float* __restrict__ out,
    long Ntot, int nblocks) {
  const int tid  = threadIdx.x;
  const int lane = tid & 63;
  const int wave = tid >> 6;
  const int gw   = blockIdx.x * NW + wave;
  const int row  = gw >> 4, seg = gw & (NSEG - 1);
  const float c  = CDEC;
  const long base = (long)row * T_DIM + seg * SEG + (long)lane * CH;

  // whitening constants (acc[0..1] published by compose_kernel dispatch)
  const double S1 = acc[0], S2 = acc[1];
  const double mean_d = S1 / (double)Ntot;
  const double var_d  = (S2 - S1 * S1 / (double)Ntot) / (double)(Ntot - 1);
  const float meanf   = (float)mean_d;
  const float invstdf = (float)(1.0 / sqrt(var_d + 1e-8));

  const float4 rv = *(const float4*)(rewards + base);
  const float4 vv = *(const float4*)(old_values + base);
  const float4 va = *(const float4*)(values + base);
  const float4 lp = *(const float4*)(logprobs + base);
  const float4 ol = *(const float4*)(old_logprobs + base);
  const int4  mk  = *(const int4*)(mask + base);
  float nv = __shfl_down(vv.x, 1);
  if (lane == 63) nv = (seg == NSEG - 1) ? 0.f : old_values[base + CH];

  const float c2 = c * c, c3 = c2 * c, c4 = c2 * c2;

  // local suffix chain
  const float L3 = rv.w + nv   - vv.w;
  const float L2 = rv.z + vv.w - vv.z + c * L3;
  const float L1 = rv.y + vv.z - vv.y + c * L2;
  const float L0 = rv.x + vv.y - vv.x + c * L1;

  float sL = L0, sM = c4;
  wave_suffix(sL, sM, lane);
  float nL = __shfl_down(sL, 1);
  float nM = __shfl_down(sM, 1);
  if (lane == 63) { nL = 0.f; nM = 1.f; }
  const float Cseg  = wsC[gw];
  const float carry = nL + nM * Cseg;

  const float A0 = L0 + carry * c4;
  const float A1 = L1 + carry * c3;
  const float A2 = L2 + carry * c2;
  const float A3 = L3 + carry * c;

  float vf_s = 0.f, pg_s = 0.f, n_s = 0.f;
#define STEP(AV, OV, VA, LP, OL, MK)                                           \
  {                                                                            \
    const float mf  = (float)MK;                                               \
    const float ret = AV + OV;                                                 \
    const float vc2 = fminf(fmaxf(VA, OV - CLIPV), OV + CLIPV);                \
    const float d1  = VA - ret, d2 = vc2 - ret;                                \
    vf_s += fmaxf(d1 * d1, d2 * d2) * mf;                                      \
    const float ratio = expf((LP - OL) * mf);                                  \
    const float a     = (AV - meanf) * invstdf;                                \
    const float p1    = -a * ratio;                                            \
    const float p2    = -a * fminf(fmaxf(ratio, 1.f - CLIPR), 1.f + CLIPR);    \
    pg_s += fmaxf(p1, p2) * mf;                                                \
    n_s  += mf;                                                                \
  }
  STEP(A0, vv.x, va.x, lp.x, ol.x, mk.x)
  STEP(A1, vv.y, va.y, lp.y, ol.y, mk.y)
  STEP(A2, vv.z, va.z, lp.z, ol.z, mk.z)
  STEP(A3, vv.w, va.w, lp.w, ol.w, mk.w)
#undef STEP

  __shared__ double red[3][NW];
  double r0 = wave_sum_d((double)vf_s);
  double r1 = wave_sum_d((double)pg_s);
  double r2 = wave_sum_d((double)n_s);
  if (lane == 0) { red[0][wave] = r0; red[1][wave] = r1; red[2][wave] = r2; }
  __syncthreads();
  if (tid == 0) {
    double t0 = 0.0, t1 = 0.0, t2 = 0.0;
#pragma unroll
    for (int w = 0; w < NW; ++w) {
      t0 += red[0][w]; t1 += red[1][w]; t2 += red[2][w];
    }
    atomicAdd(&acc[2], t0);
    atomicAdd(&acc[3], t1);
    atomicAdd(&acc[4], t2);
    __threadfence();
    unsigned long long prev = __hip_atomic_fetch_add(
        (unsigned long long*)&acc[5], 1ull,
        __ATOMIC_ACQ_REL, __HIP_MEMORY_SCOPE_AGENT);
    if (prev == (unsigned long long)(nblocks - 1)) {   // last block finalizes
      __threadfence();
      const double vf = __hip_atomic_load(&acc[2], __ATOMIC_RELAXED,
                                          __HIP_MEMORY_SCOPE_AGENT);
      const double pg = __hip_atomic_load(&acc[3], __ATOMIC_RELAXED,
                                          __HIP_MEMORY_SCOPE_AGENT);
      const double n  = __hip_atomic_load(&acc[4], __ATOMIC_RELAXED,
                                          __HIP_MEMORY_SCOPE_AGENT);
      out[0] = (float)(pg / n + 0.5 * vf / n);   // VF_COEF = 1.0
    }
  }
}

extern "C" void kernel_launch(void* const* d_in, const int* in_sizes, int n_in,
                              void* d_out, int out_size, void* d_ws, size_t ws_size,
                              hipStream_t stream) {
  const float* logprobs     = (const float*)d_in[0];
  const float* values       = (const float*)d_in[1];
  const float* old_logprobs = (const float*)d_in[2];
  const float* old_values   = (const float*)d_in[3];
  const float* rewards      = (const float*)d_in[4];
  const int*   mask         = (const int*)d_in[5];

  const long total = (long)in_sizes[0];
  const int  nrows = (int)(total / T_DIM);
  const int  NS    = nrows * NSEG;

  double* acc = (double*)d_ws;
  float*  f   = (float*)((char*)d_ws + 64);
  float *wsL = f, *wsM = f + NS, *wsB0 = f + 2L * NS, *wsB1 = f + 3L * NS,
        *wsQ0 = f + 4L * NS, *wsQ1 = f + 5L * NS, *wsQ2 = f + 6L * NS,
        *wsC = f + 7L * NS;

  hipMemsetAsync(acc, 0, 6 * sizeof(double), stream);

  const int nblkA = NS / NW;                       // 4096
  const int nblkC = (nrows + BT - 1) / BT;         // 4
  const int nblkB = NS / NW;                       // 4096

  seg_stats_kernel<<<nblkA, BT, 0, stream>>>(old_values, rewards, wsL, wsM,
                                             wsB0, wsB1, wsQ0, wsQ1, wsQ2);
  compose_kernel<<<nblkC, BT, 0, stream>>>(wsL, wsM, wsB0, wsB1, wsQ0, wsQ1,
                                           wsQ2, wsC, acc, nrows);
  loss_kernel<<<nblkB, BT, 0, stream>>>(logprobs, values, old_logprobs,
                                        old_values, rewards, mask, wsC, acc,
                                        (float*)d_out, total, nblkB);
}

// Round 5
// 197.707 us; speedup vs baseline: 2.1355x; 2.1355x over previous
//
#include <hip/hip_runtime.h>

// PPO model loss — wave-autonomous 3-level GAE decomposition.
// R5: NO fences / acq-rel / in-kernel finalize (R4's per-block agent-scope
// cache-maintenance ops thrashed L2: 310us loss kernel at 3% VALU). Plain
// relaxed atomicAdd + separate finalize kernel, SEG=512 / CH=8 per lane.
//
// A1 seg_stats : per-segment (512 elems / wave) affine (L, c^512) + whitening
//                sums as closed-form coeffs in the segment carry C.
// A2 compose   : per-row serial composition of 8 segment affines -> carries
//                wsC[row][seg]; accumulates global sum/sumsq.
// B  loss      : per-segment wave regenerates adv from wsC + 64-lane shfl
//                scan, computes clipped vf/pg losses -> atomics.
// C  finalize  : 1 thread.
//
// ws layout: [0..47] double acc: 0=s1 1=s2 2=vf 3=pg 4=n
//            [64..]  8 float arrays of NS=rows*NSEG: L,M,b0,b1,q0,q1,q2,C

static constexpr int T_DIM = 4096;
static constexpr int SEG   = 512;           // elements per segment (one wave)
static constexpr int NSEG  = T_DIM / SEG;   // 8 segments per row
static constexpr int CH    = 8;             // elements per lane
static constexpr int BT    = 256;           // threads per block
static constexpr int NW    = BT / 64;       // 4 waves per block

#define CDEC 0.95f
#define CLIPR 0.2f
#define CLIPV 0.2f

__device__ __forceinline__ double wave_sum_d(double v) {
#pragma unroll
  for (int d = 32; d > 0; d >>= 1) v += __shfl_down(v, d);
  return v;
}

__device__ __forceinline__ float wave_sum_f(float v) {
#pragma unroll
  for (int d = 32; d > 0; d >>= 1) v += __shfl_down(v, d);
  return v;
}

// inclusive suffix scan of affine (L, M) across the 64-lane wave
__device__ __forceinline__ void wave_suffix(float& sL, float& sM, int lane) {
#pragma unroll
  for (int d = 1; d < 64; d <<= 1) {
    float oL = __shfl_down(sL, d);
    float oM = __shfl_down(sM, d);
    if (lane + d < 64) { sL += sM * oL; sM *= oM; }
  }
}

// ---------------- A1: per-segment affine + stats coefficients --------------
__global__ __launch_bounds__(BT) void seg_stats_kernel(
    const float* __restrict__ old_values,
    const float* __restrict__ rewards,
    float* __restrict__ wsL, float* __restrict__ wsM,
    float* __restrict__ wsB0, float* __restrict__ wsB1,
    float* __restrict__ wsQ0, float* __restrict__ wsQ1,
    float* __restrict__ wsQ2) {
  const int tid  = threadIdx.x;
  const int lane = tid & 63;
  const int gw   = blockIdx.x * NW + (tid >> 6);  // segment id
  const int row  = gw / NSEG, seg = gw & (NSEG - 1);
  const float c  = CDEC;
  const long base = (long)row * T_DIM + seg * SEG + (long)lane * CH;

  const float4 rv0 = *(const float4*)(rewards + base);
  const float4 rv1 = *(const float4*)(rewards + base + 4);
  const float4 vv0 = *(const float4*)(old_values + base);
  const float4 vv1 = *(const float4*)(old_values + base + 4);

  float v[CH + 1], rw[CH];
  v[0] = vv0.x; v[1] = vv0.y; v[2] = vv0.z; v[3] = vv0.w;
  v[4] = vv1.x; v[5] = vv1.y; v[6] = vv1.z; v[7] = vv1.w;
  rw[0] = rv0.x; rw[1] = rv0.y; rw[2] = rv0.z; rw[3] = rv0.w;
  rw[4] = rv1.x; rw[5] = rv1.y; rw[6] = rv1.z; rw[7] = rv1.w;
  float nv = __shfl_down(v[0], 1);
  if (lane == 63) nv = (seg == NSEG - 1) ? 0.f : old_values[base + CH];
  v[CH] = nv;

  float Qc = 0.f, Q2 = 0.f, cCH;
  {
    float pw = 1.f;
#pragma unroll
    for (int i = 0; i < CH; ++i) { pw *= c; Qc += pw; Q2 += pw * pw; }
    cCH = pw;
  }

  // local chain (t high -> low) with closed-form stat accumulators
  float L = 0.f, P = 0.f, P2 = 0.f, cross = 0.f, pw = 1.f;
#pragma unroll
  for (int j = CH - 1; j >= 0; --j) {
    const float d = rw[j] + v[j + 1] - v[j];
    L = d + c * L;
    pw *= c;
    P += L; P2 += L * L; cross += L * pw;
  }

  float sL = L, sM = cCH;
  wave_suffix(sL, sM, lane);
  float nL = __shfl_down(sL, 1);
  float nM = __shfl_down(sM, 1);
  if (lane == 63) { nL = 0.f; nM = 1.f; }

  // thread carry = nL + nM*C  =>  stats as polynomials in segment carry C
  float b0 = P + Qc * nL;
  float b1 = Qc * nM;
  float q0 = P2 + 2.f * nL * cross + Q2 * nL * nL;
  float q1 = 2.f * nM * cross + 2.f * Q2 * nL * nM;
  float q2 = Q2 * nM * nM;

  b0 = wave_sum_f(b0); b1 = wave_sum_f(b1);
  q0 = wave_sum_f(q0); q1 = wave_sum_f(q1); q2 = wave_sum_f(q2);

  if (lane == 0) {
    wsL[gw] = sL;  wsM[gw] = sM;
    wsB0[gw] = b0; wsB1[gw] = b1;
    wsQ0[gw] = q0; wsQ1[gw] = q1; wsQ2[gw] = q2;
  }
}

// ---------------- A2: per-row composition + global stats -------------------
__global__ __launch_bounds__(BT) void compose_kernel(
    const float* __restrict__ wsL, const float* __restrict__ wsM,
    const float* __restrict__ wsB0, const float* __restrict__ wsB1,
    const float* __restrict__ wsQ0, const float* __restrict__ wsQ1,
    const float* __restrict__ wsQ2,
    float* __restrict__ wsC, double* __restrict__ acc, int nrows) {
  const int tid  = threadIdx.x;
  const int lane = tid & 63;
  const int wave = tid >> 6;
  const int row  = blockIdx.x * BT + tid;

  double s1 = 0.0, s2 = 0.0;
  if (row < nrows) {
    const int i0 = row * NSEG;
    float C = 0.f;   // carry into segment s
    for (int s = NSEG - 1; s >= 0; --s) {
      wsC[i0 + s] = C;
      s1 += (double)(wsB0[i0 + s] + wsB1[i0 + s] * C);
      s2 += (double)(wsQ0[i0 + s] + (wsQ1[i0 + s] + wsQ2[i0 + s] * C) * C);
      C = wsL[i0 + s] + wsM[i0 + s] * C;
    }
  }

  __shared__ double red[2][NW];
  double r1 = wave_sum_d(s1);
  double r2 = wave_sum_d(s2);
  if (lane == 0) { red[0][wave] = r1; red[1][wave] = r2; }
  __syncthreads();
  if (tid == 0) {
    double t1 = 0.0, t2 = 0.0;
#pragma unroll
    for (int w = 0; w < NW; ++w) { t1 += red[0][w]; t2 += red[1][w]; }
    atomicAdd(&acc[0], t1);
    atomicAdd(&acc[1], t2);
  }
}

// ---------------- B: losses ------------------------------------------------
__global__ __launch_bounds__(BT) void loss_kernel(
    const float* __restrict__ logprobs,
    const float* __restrict__ values,
    const float* __restrict__ old_logprobs,
    const float* __restrict__ old_values,
    const float* __restrict__ rewards,
    const int*   __restrict__ mask,
    const float* __restrict__ wsC,
    double* __restrict__ acc, long Ntot) {
  const int tid  = threadIdx.x;
  const int lane = tid & 63;
  const int wave = tid >> 6;
  const int gw   = blockIdx.x * NW + wave;
  const int row  = gw / NSEG, seg = gw & (NSEG - 1);
  const float c  = CDEC;
  const long base = (long)row * T_DIM + seg * SEG + (long)lane * CH;

  const double S1 = acc[0], S2 = acc[1];
  const double mean_d = S1 / (double)Ntot;
  const double var_d  = (S2 - S1 * S1 / (double)Ntot) / (double)(Ntot - 1);
  const float meanf   = (float)mean_d;
  const float invstdf = (float)(1.0 / sqrt(var_d + 1e-8));

  const float4 rv0 = *(const float4*)(rewards + base);
  const float4 rv1 = *(const float4*)(rewards + base + 4);
  const float4 vv0 = *(const float4*)(old_values + base);
  const float4 vv1 = *(const float4*)(old_values + base + 4);
  const float4 va0 = *(const float4*)(values + base);
  const float4 va1 = *(const float4*)(values + base + 4);
  const float4 lp0 = *(const float4*)(logprobs + base);
  const float4 lp1 = *(const float4*)(logprobs + base + 4);
  const float4 ol0 = *(const float4*)(old_logprobs + base);
  const float4 ol1 = *(const float4*)(old_logprobs + base + 4);
  const int4  mk0  = *(const int4*)(mask + base);
  const int4  mk1  = *(const int4*)(mask + base + 4);

  float v[CH + 1], rw[CH], va[CH], lp[CH], ol[CH];
  int mk[CH];
  v[0] = vv0.x; v[1] = vv0.y; v[2] = vv0.z; v[3] = vv0.w;
  v[4] = vv1.x; v[5] = vv1.y; v[6] = vv1.z; v[7] = vv1.w;
  rw[0] = rv0.x; rw[1] = rv0.y; rw[2] = rv0.z; rw[3] = rv0.w;
  rw[4] = rv1.x; rw[5] = rv1.y; rw[6] = rv1.z; rw[7] = rv1.w;
  va[0] = va0.x; va[1] = va0.y; va[2] = va0.z; va[3] = va0.w;
  va[4] = va1.x; va[5] = va1.y; va[6] = va1.z; va[7] = va1.w;
  lp[0] = lp0.x; lp[1] = lp0.y; lp[2] = lp0.z; lp[3] = lp0.w;
  lp[4] = lp1.x; lp[5] = lp1.y; lp[6] = lp1.z; lp[7] = lp1.w;
  ol[0] = ol0.x; ol[1] = ol0.y; ol[2] = ol0.z; ol[3] = ol0.w;
  ol[4] = ol1.x; ol[5] = ol1.y; ol[6] = ol1.z; ol[7] = ol1.w;
  mk[0] = mk0.x; mk[1] = mk0.y; mk[2] = mk0.z; mk[3] = mk0.w;
  mk[4] = mk1.x; mk[5] = mk1.y; mk[6] = mk1.z; mk[7] = mk1.w;

  float nv = __shfl_down(v[0], 1);
  if (lane == 63) nv = (seg == NSEG - 1) ? 0.f : old_values[base + CH];
  v[CH] = nv;

  float cCH;
  { float pw = 1.f;
#pragma unroll
    for (int i = 0; i < CH; ++i) pw *= c;
    cCH = pw; }

  // local suffix chain
  float L[CH];
  L[CH - 1] = rw[CH - 1] + v[CH] - v[CH - 1];
#pragma unroll
  for (int j = CH - 2; j >= 0; --j)
    L[j] = (rw[j] + v[j + 1] - v[j]) + c * L[j + 1];

  float sL = L[0], sM = cCH;
  wave_suffix(sL, sM, lane);
  float nL = __shfl_down(sL, 1);
  float nM = __shfl_down(sM, 1);
  if (lane == 63) { nL = 0.f; nM = 1.f; }
  const float carry = nL + nM * wsC[gw];

  float vf_s = 0.f, pg_s = 0.f, n_s = 0.f;
  float cpw = 1.f;
#pragma unroll
  for (int j = CH - 1; j >= 0; --j) {
    cpw *= c;                       // c^(CH-j)
    const float A   = L[j] + carry * cpw;
    const float mf  = (float)mk[j];
    const float ret = A + v[j];
    const float vc2 = fminf(fmaxf(va[j], v[j] - CLIPV), v[j] + CLIPV);
    const float d1  = va[j] - ret, d2 = vc2 - ret;
    vf_s += fmaxf(d1 * d1, d2 * d2) * mf;
    const float ratio = expf((lp[j] - ol[j]) * mf);
    const float a     = (A - meanf) * invstdf;
    const float p1    = -a * ratio;
    const float p2    = -a * fminf(fmaxf(ratio, 1.f - CLIPR), 1.f + CLIPR);
    pg_s += fmaxf(p1, p2) * mf;
    n_s  += mf;
  }

  __shared__ double red[3][NW];
  double r0 = wave_sum_d((double)vf_s);
  double r1 = wave_sum_d((double)pg_s);
  double r2 = wave_sum_d((double)n_s);
  if (lane == 0) { red[0][wave] = r0; red[1][wave] = r1; red[2][wave] = r2; }
  __syncthreads();
  if (tid == 0) {
    double t0 = 0.0, t1 = 0.0, t2 = 0.0;
#pragma unroll
    for (int w = 0; w < NW; ++w) {
      t0 += red[0][w]; t1 += red[1][w]; t2 += red[2][w];
    }
    atomicAdd(&acc[2], t0);
    atomicAdd(&acc[3], t1);
    atomicAdd(&acc[4], t2);
  }
}

// ---------------- C: finalize ----------------------------------------------
__global__ void finalize_kernel(const double* __restrict__ acc,
                                float* __restrict__ out) {
  if (threadIdx.x == 0 && blockIdx.x == 0) {
    const double n = acc[4];
    out[0] = (float)(acc[3] / n + 0.5 * acc[2] / n);   // VF_COEF = 1.0
  }
}

extern "C" void kernel_launch(void* const* d_in, const int* in_sizes, int n_in,
                              void* d_out, int out_size, void* d_ws, size_t ws_size,
                              hipStream_t stream) {
  const float* logprobs     = (const float*)d_in[0];
  const float* values       = (const float*)d_in[1];
  const float* old_logprobs = (const float*)d_in[2];
  const float* old_values   = (const float*)d_in[3];
  const float* rewards      = (const float*)d_in[4];
  const int*   mask         = (const int*)d_in[5];

  const long total = (long)in_sizes[0];
  const int  nrows = (int)(total / T_DIM);
  const int  NS    = nrows * NSEG;

  double* acc = (double*)d_ws;
  float*  f   = (float*)((char*)d_ws + 64);
  float *wsL = f, *wsM = f + NS, *wsB0 = f + 2L * NS, *wsB1 = f + 3L * NS,
        *wsQ0 = f + 4L * NS, *wsQ1 = f + 5L * NS, *wsQ2 = f + 6L * NS,
        *wsC = f + 7L * NS;

  hipMemsetAsync(acc, 0, 5 * sizeof(double), stream);

  const int nblkA = NS / NW;
  const int nblkC = (nrows + BT - 1) / BT;

  seg_stats_kernel<<<nblkA, BT, 0, stream>>>(old_values, rewards, wsL, wsM,
                                             wsB0, wsB1, wsQ0, wsQ1, wsQ2);
  compose_kernel<<<nblkC, BT, 0, stream>>>(wsL, wsM, wsB0, wsB1, wsQ0, wsQ1,
                                           wsQ2, wsC, acc, nrows);
  loss_kernel<<<nblkA, BT, 0, stream>>>(logprobs, values, old_logprobs,
                                        old_values, rewards, mask, wsC, acc,
                                        total);
  finalize_kernel<<<1, 64, 0, stream>>>(acc, (float*)d_out);
}

// Round 6
// 144.166 us; speedup vs baseline: 2.9285x; 1.3714x over previous
//
#include <hip/hip_runtime.h>

// PPO model loss — wave-autonomous GAE, zero hot-path atomics.
// R6: R5's loss regression traced to 12K contended double atomicAdds at block
// exit. Now: K3 writes per-block partials to ws slots (no atomics), compose is
// ONE block that also emits mean/invstd floats (no memset, no double math in
// K3), loss uses BT=1024 (512 blocks), and — when ws_size permits — K1 stores
// per-element local-scan values L[j] + per-thread carry coeffs so K3 is pure
// streaming with NO shfl scan at all.
//
// ws layout:
//   [0)      2 floats: meanf, invstdf                (written by compose)
//   [64)     8 float arrays of NS: L,M,b0,b1,q0,q1,q2 (transposed [seg][row]),
//            then wsC ([row][seg])
//   [262208) 3*nblk3 doubles: per-block (vf,pg,n) partials
//   [274496) big path: Lbuf (NT floats) + thrLM (NT/CH float2)

static constexpr int T_DIM = 4096;
static constexpr int SEG   = 512;           // elements per segment (one wave)
static constexpr int NSEG  = T_DIM / SEG;   // 8 segments per row
static constexpr int CH    = 8;             // elements per lane
static constexpr int BT1   = 256;           // K1 block
static constexpr int NW1   = BT1 / 64;
static constexpr int BT3   = 1024;          // K3 block
static constexpr int NW3   = BT3 / 64;      // 16

#define CDEC 0.95f
#define CLIPR 0.2f
#define CLIPV 0.2f

__device__ __forceinline__ double wave_sum_d(double v) {
#pragma unroll
  for (int d = 32; d > 0; d >>= 1) v += __shfl_down(v, d);
  return v;
}
__device__ __forceinline__ float wave_sum_f(float v) {
#pragma unroll
  for (int d = 32; d > 0; d >>= 1) v += __shfl_down(v, d);
  return v;
}
// inclusive suffix scan of affine (L, M) across the 64-lane wave
__device__ __forceinline__ void wave_suffix(float& sL, float& sM, int lane) {
#pragma unroll
  for (int d = 1; d < 64; d <<= 1) {
    float oL = __shfl_down(sL, d);
    float oM = __shfl_down(sM, d);
    if (lane + d < 64) { sL += sM * oL; sM *= oM; }
  }
}

// ---------------- K1: per-segment affine + stats coeffs (+L store) ---------
__global__ __launch_bounds__(BT1) void seg_stats_kernel(
    const float* __restrict__ old_values,
    const float* __restrict__ rewards,
    float* __restrict__ wsL, float* __restrict__ wsM,
    float* __restrict__ wsB0, float* __restrict__ wsB1,
    float* __restrict__ wsQ0, float* __restrict__ wsQ1,
    float* __restrict__ wsQ2,
    float* __restrict__ Lbuf, float2* __restrict__ thrLM,
    int nrows, int store_l) {
  const int tid  = threadIdx.x;
  const int lane = tid & 63;
  const int gw   = blockIdx.x * NW1 + (tid >> 6);  // segment id
  const int row  = gw / NSEG, seg = gw & (NSEG - 1);
  const float c  = CDEC;
  const long base = (long)gw * SEG + (long)lane * CH;  // = row*T + seg*SEG + ..

  const float4 rv0 = *(const float4*)(rewards + base);
  const float4 rv1 = *(const float4*)(rewards + base + 4);
  const float4 vv0 = *(const float4*)(old_values + base);
  const float4 vv1 = *(const float4*)(old_values + base + 4);

  float v[CH + 1], rw[CH];
  v[0] = vv0.x; v[1] = vv0.y; v[2] = vv0.z; v[3] = vv0.w;
  v[4] = vv1.x; v[5] = vv1.y; v[6] = vv1.z; v[7] = vv1.w;
  rw[0] = rv0.x; rw[1] = rv0.y; rw[2] = rv0.z; rw[3] = rv0.w;
  rw[4] = rv1.x; rw[5] = rv1.y; rw[6] = rv1.z; rw[7] = rv1.w;
  float nv = __shfl_down(v[0], 1);
  if (lane == 63) nv = (seg == NSEG - 1) ? 0.f : old_values[base + CH];
  v[CH] = nv;

  float Qc = 0.f, Q2 = 0.f, cCH;
  {
    float pw = 1.f;
#pragma unroll
    for (int i = 0; i < CH; ++i) { pw *= c; Qc += pw; Q2 += pw * pw; }
    cCH = pw;
  }

  // local suffix scan (zero carry-in)
  float L[CH];
  L[CH - 1] = rw[CH - 1] + v[CH] - v[CH - 1];
#pragma unroll
  for (int j = CH - 2; j >= 0; --j)
    L[j] = (rw[j] + v[j + 1] - v[j]) + c * L[j + 1];

  float P = 0.f, P2 = 0.f, cross = 0.f;
  {
    float pw = 1.f;
#pragma unroll
    for (int j = CH - 1; j >= 0; --j) {
      pw *= c;                                  // c^(CH-j)
      P += L[j]; P2 += L[j] * L[j]; cross += L[j] * pw;
    }
  }

  float sL = L[0], sM = cCH;
  wave_suffix(sL, sM, lane);
  float nLc = __shfl_down(sL, 1);
  float nMc = __shfl_down(sM, 1);
  if (lane == 63) { nLc = 0.f; nMc = 1.f; }

  if (store_l) {
    *(float4*)(Lbuf + base)     = make_float4(L[0], L[1], L[2], L[3]);
    *(float4*)(Lbuf + base + 4) = make_float4(L[4], L[5], L[6], L[7]);
    thrLM[(long)gw * 64 + lane] = make_float2(nLc, nMc);
  }

  // stats as polynomials in segment carry C (thread carry = nLc + nMc*C)
  float b0 = P + Qc * nLc;
  float b1 = Qc * nMc;
  float q0 = P2 + 2.f * nLc * cross + Q2 * nLc * nLc;
  float q1 = 2.f * nMc * cross + 2.f * Q2 * nLc * nMc;
  float q2 = Q2 * nMc * nMc;

  b0 = wave_sum_f(b0); b1 = wave_sum_f(b1);
  q0 = wave_sum_f(q0); q1 = wave_sum_f(q1); q2 = wave_sum_f(q2);

  if (lane == 0) {
    const int t = seg * nrows + row;   // transposed for coalesced compose
    wsL[t] = sL;  wsM[t] = sM;
    wsB0[t] = b0; wsB1[t] = b1;
    wsQ0[t] = q0; wsQ1[t] = q1; wsQ2[t] = q2;
  }
}

// ---------------- K2: single-block compose + whitening constants -----------
__global__ __launch_bounds__(1024) void compose_kernel(
    const float* __restrict__ wsL, const float* __restrict__ wsM,
    const float* __restrict__ wsB0, const float* __restrict__ wsB1,
    const float* __restrict__ wsQ0, const float* __restrict__ wsQ1,
    const float* __restrict__ wsQ2,
    float* __restrict__ wsC, float* __restrict__ scal,
    int nrows, long Ntot) {
  const int tid  = threadIdx.x;
  const int lane = tid & 63;
  const int wave = tid >> 6;

  double s1 = 0.0, s2 = 0.0;
  if (tid < nrows) {
    const int row = tid;
    float C = 0.f;   // carry into segment s
    for (int s = NSEG - 1; s >= 0; --s) {
      const int t = s * nrows + row;
      wsC[row * NSEG + s] = C;
      s1 += (double)(wsB0[t] + wsB1[t] * C);
      s2 += (double)(wsQ0[t] + (wsQ1[t] + wsQ2[t] * C) * C);
      C = wsL[t] + wsM[t] * C;
    }
  }

  __shared__ double red[2][16];
  double r1 = wave_sum_d(s1);
  double r2 = wave_sum_d(s2);
  if (lane == 0) { red[0][wave] = r1; red[1][wave] = r2; }
  __syncthreads();
  if (tid == 0) {
    double S1 = 0.0, S2 = 0.0;
#pragma unroll
    for (int w = 0; w < 16; ++w) { S1 += red[0][w]; S2 += red[1][w]; }
    const double mean = S1 / (double)Ntot;
    const double var  = (S2 - S1 * S1 / (double)Ntot) / (double)(Ntot - 1);
    scal[0] = (float)mean;
    scal[1] = (float)(1.0 / sqrt(var + 1e-8));
  }
}

// shared loss body: needs L[CH], v[CH], va[], lp[], ol[], mk[], carry, meanf,
// invstdf, c in scope; defines vf_s, pg_s, n_s.
#define LOSS_BODY                                                              \
  float vf_s = 0.f, pg_s = 0.f, n_s = 0.f;                                     \
  {                                                                            \
    float cpw = 1.f;                                                           \
    _Pragma("unroll") for (int j = CH - 1; j >= 0; --j) {                      \
      cpw *= c;                                                                \
      const float A   = L[j] + carry * cpw;                                    \
      const float mf  = (float)mk[j];                                          \
      const float ret = A + v[j];                                              \
      const float vc2 = fminf(fmaxf(va[j], v[j] - CLIPV), v[j] + CLIPV);       \
      const float d1  = va[j] - ret, d2 = vc2 - ret;                           \
      vf_s += fmaxf(d1 * d1, d2 * d2) * mf;                                    \
      const float ratio = expf((lp[j] - ol[j]) * mf);                          \
      const float a     = (A - meanf) * invstdf;                               \
      const float p1    = -a * ratio;                                          \
      const float p2    = -a * fminf(fmaxf(ratio, 1.f - CLIPR), 1.f + CLIPR);  \
      pg_s += fmaxf(p1, p2) * mf;                                              \
      n_s  += mf;                                                              \
    }                                                                          \
  }

#define LOSS_REDUCE                                                            \
  {                                                                            \
    __shared__ double red[3][NW3];                                             \
    double r0 = wave_sum_d((double)vf_s);                                      \
    double r1 = wave_sum_d((double)pg_s);                                      \
    double r2 = wave_sum_d((double)n_s);                                       \
    if (lane == 0) { red[0][wave] = r0; red[1][wave] = r1; red[2][wave] = r2; }\
    __syncthreads();                                                           \
    if (tid == 0) {                                                            \
      double t0 = 0.0, t1 = 0.0, t2 = 0.0;                                     \
      _Pragma("unroll") for (int w = 0; w < NW3; ++w) {                        \
        t0 += red[0][w]; t1 += red[1][w]; t2 += red[2][w];                     \
      }                                                                        \
      part[3 * blockIdx.x + 0] = t0;                                           \
      part[3 * blockIdx.x + 1] = t1;                                           \
      part[3 * blockIdx.x + 2] = t2;                                           \
    }                                                                          \
  }

// ---------------- K3a: scan-free loss (uses stored L / thrLM) --------------
__global__ __launch_bounds__(BT3) void loss_stored_kernel(
    const float* __restrict__ logprobs,
    const float* __restrict__ values,
    const float* __restrict__ old_logprobs,
    const float* __restrict__ old_values,
    const int*   __restrict__ mask,
    const float* __restrict__ Lbuf, const float2* __restrict__ thrLM,
    const float* __restrict__ wsC, const float* __restrict__ scal,
    double* __restrict__ part) {
  const int tid  = threadIdx.x;
  const int lane = tid & 63;
  const int wave = tid >> 6;
  const int gw   = blockIdx.x * NW3 + wave;
  const float c  = CDEC;
  const long base = (long)gw * SEG + (long)lane * CH;

  const float meanf = scal[0], invstdf = scal[1];

  const float4 Lb0 = *(const float4*)(Lbuf + base);
  const float4 Lb1 = *(const float4*)(Lbuf + base + 4);
  const float4 vv0 = *(const float4*)(old_values + base);
  const float4 vv1 = *(const float4*)(old_values + base + 4);
  const float4 va0 = *(const float4*)(values + base);
  const float4 va1 = *(const float4*)(values + base + 4);
  const float4 lp0 = *(const float4*)(logprobs + base);
  const float4 lp1 = *(const float4*)(logprobs + base + 4);
  const float4 ol0 = *(const float4*)(old_logprobs + base);
  const float4 ol1 = *(const float4*)(old_logprobs + base + 4);
  const int4  mk0  = *(const int4*)(mask + base);
  const int4  mk1  = *(const int4*)(mask + base + 4);
  const float2 lm  = thrLM[(long)gw * 64 + lane];
  const float carry = lm.x + lm.y * wsC[gw];

  float L[CH], v[CH], va[CH], lp[CH], ol[CH];
  int mk[CH];
  L[0] = Lb0.x; L[1] = Lb0.y; L[2] = Lb0.z; L[3] = Lb0.w;
  L[4] = Lb1.x; L[5] = Lb1.y; L[6] = Lb1.z; L[7] = Lb1.w;
  v[0] = vv0.x; v[1] = vv0.y; v[2] = vv0.z; v[3] = vv0.w;
  v[4] = vv1.x; v[5] = vv1.y; v[6] = vv1.z; v[7] = vv1.w;
  va[0] = va0.x; va[1] = va0.y; va[2] = va0.z; va[3] = va0.w;
  va[4] = va1.x; va[5] = va1.y; va[6] = va1.z; va[7] = va1.w;
  lp[0] = lp0.x; lp[1] = lp0.y; lp[2] = lp0.z; lp[3] = lp0.w;
  lp[4] = lp1.x; lp[5] = lp1.y; lp[6] = lp1.z; lp[7] = lp1.w;
  ol[0] = ol0.x; ol[1] = ol0.y; ol[2] = ol0.z; ol[3] = ol0.w;
  ol[4] = ol1.x; ol[5] = ol1.y; ol[6] = ol1.z; ol[7] = ol1.w;
  mk[0] = mk0.x; mk[1] = mk0.y; mk[2] = mk0.z; mk[3] = mk0.w;
  mk[4] = mk1.x; mk[5] = mk1.y; mk[6] = mk1.z; mk[7] = mk1.w;

  LOSS_BODY
  LOSS_REDUCE
}

// ---------------- K3b: rescan loss (small-ws fallback) ---------------------
__global__ __launch_bounds__(BT3) void loss_rescan_kernel(
    const float* __restrict__ logprobs,
    const float* __restrict__ values,
    const float* __restrict__ old_logprobs,
    const float* __restrict__ old_values,
    const float* __restrict__ rewards,
    const int*   __restrict__ mask,
    const float* __restrict__ wsC, const float* __restrict__ scal,
    double* __restrict__ part) {
  const int tid  = threadIdx.x;
  const int lane = tid & 63;
  const int wave = tid >> 6;
  const int gw   = blockIdx.x * NW3 + wave;
  const int seg  = gw & (NSEG - 1);
  const float c  = CDEC;
  const long base = (long)gw * SEG + (long)lane * CH;

  const float meanf = scal[0], invstdf = scal[1];

  const float4 rv0 = *(const float4*)(rewards + base);
  const float4 rv1 = *(const float4*)(rewards + base + 4);
  const float4 vv0 = *(const float4*)(old_values + base);
  const float4 vv1 = *(const float4*)(old_values + base + 4);
  const float4 va0 = *(const float4*)(values + base);
  const float4 va1 = *(const float4*)(values + base + 4);
  const float4 lp0 = *(const float4*)(logprobs + base);
  const float4 lp1 = *(const float4*)(logprobs + base + 4);
  const float4 ol0 = *(const float4*)(old_logprobs + base);
  const float4 ol1 = *(const float4*)(old_logprobs + base + 4);
  const int4  mk0  = *(const int4*)(mask + base);
  const int4  mk1  = *(const int4*)(mask + base + 4);

  float vx[CH + 1], rw[CH], va[CH], lp[CH], ol[CH];
  int mk[CH];
  vx[0] = vv0.x; vx[1] = vv0.y; vx[2] = vv0.z; vx[3] = vv0.w;
  vx[4] = vv1.x; vx[5] = vv1.y; vx[6] = vv1.z; vx[7] = vv1.w;
  rw[0] = rv0.x; rw[1] = rv0.y; rw[2] = rv0.z; rw[3] = rv0.w;
  rw[4] = rv1.x; rw[5] = rv1.y; rw[6] = rv1.z; rw[7] = rv1.w;
  va[0] = va0.x; va[1] = va0.y; va[2] = va0.z; va[3] = va0.w;
  va[4] = va1.x; va[5] = va1.y; va[6] = va1.z; va[7] = va1.w;
  lp[0] = lp0.x; lp[1] = lp0.y; lp[2] = lp0.z; lp[3] = lp0.w;
  lp[4] = lp1.x; lp[5] = lp1.y; lp[6] = lp1.z; lp[7] = lp1.w;
  ol[0] = ol0.x; ol[1] = ol0.y; ol[2] = ol0.z; ol[3] = ol0.w;
  ol[4] = ol1.x; ol[5] = ol1.y; ol[6] = ol1.z; ol[7] = ol1.w;
  mk[0] = mk0.x; mk[1] = mk0.y; mk[2] = mk0.z; mk[3] = mk0.w;
  mk[4] = mk1.x; mk[5] = mk1.y; mk[6] = mk1.z; mk[7] = mk1.w;

  float nv = __shfl_down(vx[0], 1);
  if (lane == 63) nv = (seg == NSEG - 1) ? 0.f : old_values[base + CH];
  vx[CH] = nv;

  float cCH;
  { float pw = 1.f;
#pragma unroll
    for (int i = 0; i < CH; ++i) pw *= c;
    cCH = pw; }

  float L[CH];
  L[CH - 1] = rw[CH - 1] + vx[CH] - vx[CH - 1];
#pragma unroll
  for (int j = CH - 2; j >= 0; --j)
    L[j] = (rw[j] + vx[j + 1] - vx[j]) + c * L[j + 1];

  float sL = L[0], sM = cCH;
  wave_suffix(sL, sM, lane);
  float nLc = __shfl_down(sL, 1);
  float nMc = __shfl_down(sM, 1);
  if (lane == 63) { nLc = 0.f; nMc = 1.f; }
  const float carry = nLc + nMc * wsC[gw];

  const float* v = vx;  // LOSS_BODY uses v[j]
  LOSS_BODY
  LOSS_REDUCE
}

// ---------------- K4: finalize (reduce per-block partials) -----------------
__global__ __launch_bounds__(1024) void finalize_kernel(
    const double* __restrict__ part, int nblk, float* __restrict__ out) {
  const int tid  = threadIdx.x;
  const int lane = tid & 63;
  const int wave = tid >> 6;
  double vf = 0.0, pg = 0.0, n = 0.0;
  for (int i = tid; i < nblk; i += 1024) {
    vf += part[3 * i + 0];
    pg += part[3 * i + 1];
    n  += part[3 * i + 2];
  }
  __shared__ double red[3][16];
  vf = wave_sum_d(vf); pg = wave_sum_d(pg); n = wave_sum_d(n);
  if (lane == 0) { red[0][wave] = vf; red[1][wave] = pg; red[2][wave] = n; }
  __syncthreads();
  if (tid == 0) {
    double t0 = 0.0, t1 = 0.0, t2 = 0.0;
#pragma unroll
    for (int w = 0; w < 16; ++w) {
      t0 += red[0][w]; t1 += red[1][w]; t2 += red[2][w];
    }
    out[0] = (float)(t1 / t2 + 0.5 * t0 / t2);   // VF_COEF = 1.0
  }
}

extern "C" void kernel_launch(void* const* d_in, const int* in_sizes, int n_in,
                              void* d_out, int out_size, void* d_ws, size_t ws_size,
                              hipStream_t stream) {
  const float* logprobs     = (const float*)d_in[0];
  const float* values       = (const float*)d_in[1];
  const float* old_logprobs = (const float*)d_in[2];
  const float* old_values   = (const float*)d_in[3];
  const float* rewards      = (const float*)d_in[4];
  const int*   mask         = (const int*)d_in[5];

  const long total = (long)in_sizes[0];
  const int  nrows = (int)(total / T_DIM);
  const int  NS    = nrows * NSEG;

  char* p = (char*)d_ws;
  float* scal = (float*)p;                         // 2 floats
  float* f    = (float*)(p + 64);
  float *wsL = f, *wsM = f + NS, *wsB0 = f + 2L * NS, *wsB1 = f + 3L * NS,
        *wsQ0 = f + 4L * NS, *wsQ1 = f + 5L * NS, *wsQ2 = f + 6L * NS,
        *wsC = f + 7L * NS;
  const size_t off_part = 64 + (size_t)8 * NS * 4;         // 8-aligned
  double* part = (double*)(p + off_part);
  const int nblk3 = NS / NW3;
  const size_t off_big = off_part + (size_t)3 * nblk3 * 8;
  float*  Lbuf  = (float*)(p + off_big);
  float2* thrLM = (float2*)(Lbuf + total);
  const size_t need_big = off_big + (size_t)total * 4 + (size_t)(total / CH) * 8;
  const int big = (ws_size >= need_big) ? 1 : 0;

  const int nblk1 = NS / NW1;

  seg_stats_kernel<<<nblk1, BT1, 0, stream>>>(old_values, rewards, wsL, wsM,
                                              wsB0, wsB1, wsQ0, wsQ1, wsQ2,
                                              Lbuf, thrLM, nrows, big);
  compose_kernel<<<1, 1024, 0, stream>>>(wsL, wsM, wsB0, wsB1, wsQ0, wsQ1,
                                         wsQ2, wsC, scal, nrows, total);
  if (big) {
    loss_stored_kernel<<<nblk3, BT3, 0, stream>>>(logprobs, values,
                                                  old_logprobs, old_values,
                                                  mask, Lbuf, thrLM, wsC, scal,
                                                  part);
  } else {
    loss_rescan_kernel<<<nblk3, BT3, 0, stream>>>(logprobs, values,
                                                  old_logprobs, old_values,
                                                  rewards, mask, wsC, scal,
                                                  part);
  }
  finalize_kernel<<<1, 1024, 0, stream>>>(part, nblk3, (float*)d_out);
}

// Round 7
// 137.145 us; speedup vs baseline: 3.0785x; 1.0512x over previous
//
#include <hip/hip_runtime.h>

// PPO model loss — wave-autonomous GAE, zero hot-path atomics, rescan-only.
// R7: dropped the stored-L path (R6): storing L[j]+thrLM moved MORE bytes
// (21MB write + 21MB read) than rescanning rewards/old_values, which are
// L2/L3-warm from K1. Loss block = 512 threads (8 waves) for 2+ blocks/CU.
//
// K1 seg_stats : per-segment (512/wave) affine (L, c^512) + whitening sums as
//                closed-form polynomials in the segment carry C.
// K2 compose   : ONE block; per-row serial composition of 8 segment affines
//                -> wsC carries + global mean/invstd floats.
// K3 loss      : per-segment wave rescans (shfl suffix scan), regenerates adv,
//                clipped vf/pg losses -> per-block partials (no atomics).
// K4 finalize  : reduce partials, write scalar loss.
//
// ws layout:
//   [0)    2 floats: meanf, invstdf (written by K2)
//   [64)   8 float arrays of NS: L,M,b0,b1,q0,q1,q2 (transposed [seg][row]),
//          wsC ([row][seg])
//   then   3*nblk3 doubles: per-block (vf,pg,n) partials

static constexpr int T_DIM = 4096;
static constexpr int SEG   = 512;           // elements per segment (one wave)
static constexpr int NSEG  = T_DIM / SEG;   // 8 segments per row
static constexpr int CH    = 8;             // elements per lane
static constexpr int BT1   = 256;           // K1 block
static constexpr int NW1   = BT1 / 64;
static constexpr int BT3   = 512;           // K3 block
static constexpr int NW3   = BT3 / 64;      // 8

#define CDEC 0.95f
#define CLIPR 0.2f
#define CLIPV 0.2f

__device__ __forceinline__ double wave_sum_d(double v) {
#pragma unroll
  for (int d = 32; d > 0; d >>= 1) v += __shfl_down(v, d);
  return v;
}
__device__ __forceinline__ float wave_sum_f(float v) {
#pragma unroll
  for (int d = 32; d > 0; d >>= 1) v += __shfl_down(v, d);
  return v;
}
// inclusive suffix scan of affine (L, M) across the 64-lane wave
__device__ __forceinline__ void wave_suffix(float& sL, float& sM, int lane) {
#pragma unroll
  for (int d = 1; d < 64; d <<= 1) {
    float oL = __shfl_down(sL, d);
    float oM = __shfl_down(sM, d);
    if (lane + d < 64) { sL += sM * oL; sM *= oM; }
  }
}

// ---------------- K1: per-segment affine + stats coefficients --------------
__global__ __launch_bounds__(BT1) void seg_stats_kernel(
    const float* __restrict__ old_values,
    const float* __restrict__ rewards,
    float* __restrict__ wsL, float* __restrict__ wsM,
    float* __restrict__ wsB0, float* __restrict__ wsB1,
    float* __restrict__ wsQ0, float* __restrict__ wsQ1,
    float* __restrict__ wsQ2, int nrows) {
  const int tid  = threadIdx.x;
  const int lane = tid & 63;
  const int gw   = blockIdx.x * NW1 + (tid >> 6);  // segment id
  const int row  = gw / NSEG, seg = gw & (NSEG - 1);
  const float c  = CDEC;
  const long base = (long)gw * SEG + (long)lane * CH;

  const float4 rv0 = *(const float4*)(rewards + base);
  const float4 rv1 = *(const float4*)(rewards + base + 4);
  const float4 vv0 = *(const float4*)(old_values + base);
  const float4 vv1 = *(const float4*)(old_values + base + 4);

  float v[CH + 1], rw[CH];
  v[0] = vv0.x; v[1] = vv0.y; v[2] = vv0.z; v[3] = vv0.w;
  v[4] = vv1.x; v[5] = vv1.y; v[6] = vv1.z; v[7] = vv1.w;
  rw[0] = rv0.x; rw[1] = rv0.y; rw[2] = rv0.z; rw[3] = rv0.w;
  rw[4] = rv1.x; rw[5] = rv1.y; rw[6] = rv1.z; rw[7] = rv1.w;
  float nv = __shfl_down(v[0], 1);
  if (lane == 63) nv = (seg == NSEG - 1) ? 0.f : old_values[base + CH];
  v[CH] = nv;

  float Qc = 0.f, Q2 = 0.f, cCH;
  {
    float pw = 1.f;
#pragma unroll
    for (int i = 0; i < CH; ++i) { pw *= c; Qc += pw; Q2 += pw * pw; }
    cCH = pw;
  }

  // local suffix scan (zero carry-in)
  float L[CH];
  L[CH - 1] = rw[CH - 1] + v[CH] - v[CH - 1];
#pragma unroll
  for (int j = CH - 2; j >= 0; --j)
    L[j] = (rw[j] + v[j + 1] - v[j]) + c * L[j + 1];

  float P = 0.f, P2 = 0.f, cross = 0.f;
  {
    float pw = 1.f;
#pragma unroll
    for (int j = CH - 1; j >= 0; --j) {
      pw *= c;                                  // c^(CH-j)
      P += L[j]; P2 += L[j] * L[j]; cross += L[j] * pw;
    }
  }

  float sL = L[0], sM = cCH;
  wave_suffix(sL, sM, lane);
  float nLc = __shfl_down(sL, 1);
  float nMc = __shfl_down(sM, 1);
  if (lane == 63) { nLc = 0.f; nMc = 1.f; }

  // stats as polynomials in segment carry C (thread carry = nLc + nMc*C)
  float b0 = P + Qc * nLc;
  float b1 = Qc * nMc;
  float q0 = P2 + 2.f * nLc * cross + Q2 * nLc * nLc;
  float q1 = 2.f * nMc * cross + 2.f * Q2 * nLc * nMc;
  float q2 = Q2 * nMc * nMc;

  b0 = wave_sum_f(b0); b1 = wave_sum_f(b1);
  q0 = wave_sum_f(q0); q1 = wave_sum_f(q1); q2 = wave_sum_f(q2);

  if (lane == 0) {
    const int t = seg * nrows + row;   // transposed for coalesced compose
    wsL[t] = sL;  wsM[t] = sM;
    wsB0[t] = b0; wsB1[t] = b1;
    wsQ0[t] = q0; wsQ1[t] = q1; wsQ2[t] = q2;
  }
}

// ---------------- K2: single-block compose + whitening constants -----------
__global__ __launch_bounds__(1024) void compose_kernel(
    const float* __restrict__ wsL, const float* __restrict__ wsM,
    const float* __restrict__ wsB0, const float* __restrict__ wsB1,
    const float* __restrict__ wsQ0, const float* __restrict__ wsQ1,
    const float* __restrict__ wsQ2,
    float* __restrict__ wsC, float* __restrict__ scal,
    int nrows, long Ntot) {
  const int tid  = threadIdx.x;
  const int lane = tid & 63;
  const int wave = tid >> 6;

  double s1 = 0.0, s2 = 0.0;
  if (tid < nrows) {
    const int row = tid;
    float C = 0.f;   // carry into segment s
#pragma unroll
    for (int s = NSEG - 1; s >= 0; --s) {
      const int t = s * nrows + row;
      wsC[row * NSEG + s] = C;
      s1 += (double)(wsB0[t] + wsB1[t] * C);
      s2 += (double)(wsQ0[t] + (wsQ1[t] + wsQ2[t] * C) * C);
      C = wsL[t] + wsM[t] * C;
    }
  }

  __shared__ double red[2][16];
  double r1 = wave_sum_d(s1);
  double r2 = wave_sum_d(s2);
  if (lane == 0) { red[0][wave] = r1; red[1][wave] = r2; }
  __syncthreads();
  if (tid == 0) {
    double S1 = 0.0, S2 = 0.0;
#pragma unroll
    for (int w = 0; w < 16; ++w) { S1 += red[0][w]; S2 += red[1][w]; }
    const double mean = S1 / (double)Ntot;
    const double var  = (S2 - S1 * S1 / (double)Ntot) / (double)(Ntot - 1);
    scal[0] = (float)mean;
    scal[1] = (float)(1.0 / sqrt(var + 1e-8));
  }
}

// ---------------- K3: loss (rescan, per-block partials) --------------------
__global__ __launch_bounds__(BT3) void loss_kernel(
    const float* __restrict__ logprobs,
    const float* __restrict__ values,
    const float* __restrict__ old_logprobs,
    const float* __restrict__ old_values,
    const float* __restrict__ rewards,
    const int*   __restrict__ mask,
    const float* __restrict__ wsC, const float* __restrict__ scal,
    double* __restrict__ part) {
  const int tid  = threadIdx.x;
  const int lane = tid & 63;
  const int wave = tid >> 6;
  const int gw   = blockIdx.x * NW3 + wave;
  const int seg  = gw & (NSEG - 1);
  const float c  = CDEC;
  const long base = (long)gw * SEG + (long)lane * CH;

  const float meanf = scal[0], invstdf = scal[1];

  const float4 rv0 = *(const float4*)(rewards + base);
  const float4 rv1 = *(const float4*)(rewards + base + 4);
  const float4 vv0 = *(const float4*)(old_values + base);
  const float4 vv1 = *(const float4*)(old_values + base + 4);
  const float4 va0 = *(const float4*)(values + base);
  const float4 va1 = *(const float4*)(values + base + 4);
  const float4 lp0 = *(const float4*)(logprobs + base);
  const float4 lp1 = *(const float4*)(logprobs + base + 4);
  const float4 ol0 = *(const float4*)(old_logprobs + base);
  const float4 ol1 = *(const float4*)(old_logprobs + base + 4);
  const int4  mk0  = *(const int4*)(mask + base);
  const int4  mk1  = *(const int4*)(mask + base + 4);

  float v[CH + 1], rw[CH], va[CH], lp[CH], ol[CH];
  int mk[CH];
  v[0] = vv0.x; v[1] = vv0.y; v[2] = vv0.z; v[3] = vv0.w;
  v[4] = vv1.x; v[5] = vv1.y; v[6] = vv1.z; v[7] = vv1.w;
  rw[0] = rv0.x; rw[1] = rv0.y; rw[2] = rv0.z; rw[3] = rv0.w;
  rw[4] = rv1.x; rw[5] = rv1.y; rw[6] = rv1.z; rw[7] = rv1.w;
  va[0] = va0.x; va[1] = va0.y; va[2] = va0.z; va[3] = va0.w;
  va[4] = va1.x; va[5] = va1.y; va[6] = va1.z; va[7] = va1.w;
  lp[0] = lp0.x; lp[1] = lp0.y; lp[2] = lp0.z; lp[3] = lp0.w;
  lp[4] = lp1.x; lp[5] = lp1.y; lp[6] = lp1.z; lp[7] = lp1.w;
  ol[0] = ol0.x; ol[1] = ol0.y; ol[2] = ol0.z; ol[3] = ol0.w;
  ol[4] = ol1.x; ol[5] = ol1.y; ol[6] = ol1.z; ol[7] = ol1.w;
  mk[0] = mk0.x; mk[1] = mk0.y; mk[2] = mk0.z; mk[3] = mk0.w;
  mk[4] = mk1.x; mk[5] = mk1.y; mk[6] = mk1.z; mk[7] = mk1.w;

  float nv = __shfl_down(v[0], 1);
  if (lane == 63) nv = (seg == NSEG - 1) ? 0.f : old_values[base + CH];
  v[CH] = nv;

  float cCH;
  { float pw = 1.f;
#pragma unroll
    for (int i = 0; i < CH; ++i) pw *= c;
    cCH = pw; }

  float L[CH];
  L[CH - 1] = rw[CH - 1] + v[CH] - v[CH - 1];
#pragma unroll
  for (int j = CH - 2; j >= 0; --j)
    L[j] = (rw[j] + v[j + 1] - v[j]) + c * L[j + 1];

  float sL = L[0], sM = cCH;
  wave_suffix(sL, sM, lane);
  float nLc = __shfl_down(sL, 1);
  float nMc = __shfl_down(sM, 1);
  if (lane == 63) { nLc = 0.f; nMc = 1.f; }
  const float carry = nLc + nMc * wsC[gw];

  float vf_s = 0.f, pg_s = 0.f, n_s = 0.f;
  {
    float cpw = 1.f;
#pragma unroll
    for (int j = CH - 1; j >= 0; --j) {
      cpw *= c;                       // c^(CH-j)
      const float A   = L[j] + carry * cpw;
      const float mf  = (float)mk[j];
      const float ret = A + v[j];
      const float vc2 = fminf(fmaxf(va[j], v[j] - CLIPV), v[j] + CLIPV);
      const float d1  = va[j] - ret, d2 = vc2 - ret;
      vf_s += fmaxf(d1 * d1, d2 * d2) * mf;
      const float ratio = expf((lp[j] - ol[j]) * mf);
      const float a     = (A - meanf) * invstdf;
      const float p1    = -a * ratio;
      const float p2    = -a * fminf(fmaxf(ratio, 1.f - CLIPR), 1.f + CLIPR);
      pg_s += fmaxf(p1, p2) * mf;
      n_s  += mf;
    }
  }

  __shared__ double red[3][NW3];
  double r0 = wave_sum_d((double)vf_s);
  double r1 = wave_sum_d((double)pg_s);
  double r2 = wave_sum_d((double)n_s);
  if (lane == 0) { red[0][wave] = r0; red[1][wave] = r1; red[2][wave] = r2; }
  __syncthreads();
  if (tid == 0) {
    double t0 = 0.0, t1 = 0.0, t2 = 0.0;
#pragma unroll
    for (int w = 0; w < NW3; ++w) {
      t0 += red[0][w]; t1 += red[1][w]; t2 += red[2][w];
    }
    part[3 * blockIdx.x + 0] = t0;
    part[3 * blockIdx.x + 1] = t1;
    part[3 * blockIdx.x + 2] = t2;
  }
}

// ---------------- K4: finalize (reduce per-block partials) -----------------
__global__ __launch_bounds__(1024) void finalize_kernel(
    const double* __restrict__ part, int nblk, float* __restrict__ out) {
  const int tid  = threadIdx.x;
  const int lane = tid & 63;
  const int wave = tid >> 6;
  double vf = 0.0, pg = 0.0, n = 0.0;
  for (int i = tid; i < nblk; i += 1024) {
    vf += part[3 * i + 0];
    pg += part[3 * i + 1];
    n  += part[3 * i + 2];
  }
  __shared__ double red[3][16];
  vf = wave_sum_d(vf); pg = wave_sum_d(pg); n = wave_sum_d(n);
  if (lane == 0) { red[0][wave] = vf; red[1][wave] = pg; red[2][wave] = n; }
  __syncthreads();
  if (tid == 0) {
    double t0 = 0.0, t1 = 0.0, t2 = 0.0;
#pragma unroll
    for (int w = 0; w < 16; ++w) {
      t0 += red[0][w]; t1 += red[1][w]; t2 += red[2][w];
    }
    out[0] = (float)(t1 / t2 + 0.5 * t0 / t2);   // VF_COEF = 1.0
  }
}

extern "C" void kernel_launch(void* const* d_in, const int* in_sizes, int n_in,
                              void* d_out, int out_size, void* d_ws, size_t ws_size,
                              hipStream_t stream) {
  const float* logprobs     = (const float*)d_in[0];
  const float* values       = (const float*)d_in[1];
  const float* old_logprobs = (const float*)d_in[2];
  const float* old_values   = (const float*)d_in[3];
  const float* rewards      = (const float*)d_in[4];
  const int*   mask         = (const int*)d_in[5];

  const long total = (long)in_sizes[0];
  const int  nrows = (int)(total / T_DIM);
  const int  NS    = nrows * NSEG;

  char* p = (char*)d_ws;
  float* scal = (float*)p;                         // 2 floats
  float* f    = (float*)(p + 64);
  float *wsL = f, *wsM = f + NS, *wsB0 = f + 2L * NS, *wsB1 = f + 3L * NS,
        *wsQ0 = f + 4L * NS, *wsQ1 = f + 5L * NS, *wsQ2 = f + 6L * NS,
        *wsC = f + 7L * NS;
  const size_t off_part = 64 + (size_t)8 * NS * 4;
  double* part = (double*)(p + off_part);

  const int nblk1 = NS / NW1;
  const int nblk3 = NS / NW3;

  seg_stats_kernel<<<nblk1, BT1, 0, stream>>>(old_values, rewards, wsL, wsM,
                                              wsB0, wsB1, wsQ0, wsQ1, wsQ2,
                                              nrows);
  compose_kernel<<<1, 1024, 0, stream>>>(wsL, wsM, wsB0, wsB1, wsQ0, wsQ1,
                                         wsQ2, wsC, scal, nrows, total);
  loss_kernel<<<nblk3, BT3, 0, stream>>>(logprobs, values, old_logprobs,
                                         old_values, rewards, mask, wsC, scal,
                                         part);
  finalize_kernel<<<1, 1024, 0, stream>>>(part, nblk3, (float*)d_out);
}